// Round 1
// baseline (1102.472 us; speedup 1.0000x reference)
//
#include <hip/hip_runtime.h>

// ---------------------------------------------------------------------------
// GIN 2-layer forward, restructured as:
//   p1 = x @ w1a                  (dual-store: p1 and s1=p1)
//   s1 += scatter_add(p1[src] -> dst)           [b1a cancels in BN]
//   stats1 = colsum/colsumsq(s1) -> sc1, sh1    (BN affine)
//   h1 = relu( relu(sc1*s1+sh1) @ w1b + b1b )   (BN+ReLU fused into A-staging)
//   p2 = h1 @ w2a                 (dual-store: p2 and s2=p2)   [64 ch]
//   s2 += scatter_add(p2[src] -> dst)           [b2a cancels in BN]
//   stats2 -> sc2, sh2
//   logits = relu(sc2*s2+sh2) @ w2b + b2b  -> d_out
//   log_softmax rows of d_out in place
// ---------------------------------------------------------------------------

#define DEV_INLINE __device__ __forceinline__

DEV_INLINE void atomAddF(float* p, float v) { unsafeAtomicAdd(p, v); }

// ---------------------------------------------------------------------------
// Tiled fp32 GEMM: out[M][NC] = f(A[M][KDIM]) @ W[KDIM][NC] (+bias)(+relu)
// f = identity or per-channel BN+ReLU: relu(sc[k]*v + sh[k])
// TM=64 rows per block, 256 threads.
// ---------------------------------------------------------------------------
template <int KDIM, int NC, bool BNIN, bool BIAS, bool RELUOUT, bool DUAL>
__global__ __launch_bounds__(256) void gemm_tile(
    const float* __restrict__ A, const float* __restrict__ W,
    const float* __restrict__ sc, const float* __restrict__ sh,
    const float* __restrict__ bias,
    float* __restrict__ out0, float* __restrict__ out1, int M)
{
    constexpr int TM = 64, KC = 16;
    constexpr int CGRP = NC / 4;           // threads spanning the N dim
    constexpr int RT   = TM / (256 / CGRP);// rows per thread
    __shared__ float As[KC][TM + 4];       // transposed A chunk
    __shared__ float Bs[KC][NC + 4];

    const int t = threadIdx.x;
    const int block_row = blockIdx.x * TM;
    const int c0 = (t % CGRP) * 4;
    const int r0 = (t / CGRP) * RT;

    float acc[RT][4];
#pragma unroll
    for (int i = 0; i < RT; i++)
#pragma unroll
        for (int j = 0; j < 4; j++) acc[i][j] = 0.f;

    for (int kk = 0; kk < KDIM; kk += KC) {
        // ---- stage A (64 rows x 16 k), transposed, optional BN+ReLU ----
        {
            const int ar = t >> 2;
            const int ak = (t & 3) * 4;
            const int gr = block_row + ar;
            float4 v = make_float4(0.f, 0.f, 0.f, 0.f);
            if (gr < M) v = *(const float4*)(A + (size_t)gr * KDIM + kk + ak);
            if constexpr (BNIN) {
                float4 s4 = *(const float4*)(sc + kk + ak);
                float4 h4 = *(const float4*)(sh + kk + ak);
                v.x = fmaxf(0.f, v.x * s4.x + h4.x);
                v.y = fmaxf(0.f, v.y * s4.y + h4.y);
                v.z = fmaxf(0.f, v.z * s4.z + h4.z);
                v.w = fmaxf(0.f, v.w * s4.w + h4.w);
            }
            As[ak + 0][ar] = v.x;
            As[ak + 1][ar] = v.y;
            As[ak + 2][ar] = v.z;
            As[ak + 3][ar] = v.w;
        }
        // ---- stage B (16 k x NC) ----
        {
            constexpr int F4 = KC * NC / 4;
#pragma unroll
            for (int f = t; f < F4; f += 256) {
                const int bk = f / (NC / 4);
                const int bc = (f % (NC / 4)) * 4;
                *(float4*)&Bs[bk][bc] =
                    *(const float4*)(W + (size_t)(kk + bk) * NC + bc);
            }
        }
        __syncthreads();

#pragma unroll
        for (int k = 0; k < KC; k++) {
            const float4 b = *(const float4*)&Bs[k][c0];
#pragma unroll
            for (int i4 = 0; i4 < RT / 4; i4++) {
                const float4 a4 = *(const float4*)&As[k][r0 + i4 * 4];
                const float av[4] = {a4.x, a4.y, a4.z, a4.w};
#pragma unroll
                for (int j = 0; j < 4; j++) {
                    acc[i4 * 4 + j][0] += av[j] * b.x;
                    acc[i4 * 4 + j][1] += av[j] * b.y;
                    acc[i4 * 4 + j][2] += av[j] * b.z;
                    acc[i4 * 4 + j][3] += av[j] * b.w;
                }
            }
        }
        __syncthreads();
    }

    // ---- epilogue ----
    float4 bv = make_float4(0.f, 0.f, 0.f, 0.f);
    if constexpr (BIAS) bv = *(const float4*)(bias + c0);
#pragma unroll
    for (int i = 0; i < RT; i++) {
        const int gr = block_row + r0 + i;
        if (gr < M) {
            float4 o = make_float4(acc[i][0] + bv.x, acc[i][1] + bv.y,
                                   acc[i][2] + bv.z, acc[i][3] + bv.w);
            if constexpr (RELUOUT) {
                o.x = fmaxf(o.x, 0.f);
                o.y = fmaxf(o.y, 0.f);
                o.z = fmaxf(o.z, 0.f);
                o.w = fmaxf(o.w, 0.f);
            }
            *(float4*)(out0 + (size_t)gr * NC + c0) = o;
            if constexpr (DUAL) *(float4*)(out1 + (size_t)gr * NC + c0) = o;
        }
    }
}

// ---------------------------------------------------------------------------
// Edge scatter-add: dst_feat[dst] += src_feat[src], one wave per edge (loop).
// ---------------------------------------------------------------------------
template <int C>
__global__ __launch_bounds__(256) void scatter_add_k(
    const float* __restrict__ src_feat, float* __restrict__ dst_feat,
    const int* __restrict__ ei, int nE)
{
    const int wid  = (blockIdx.x * blockDim.x + threadIdx.x) >> 6;
    const int lane = threadIdx.x & 63;
    const int nw   = (gridDim.x * blockDim.x) >> 6;
    for (int e = wid; e < nE; e += nw) {
        const int s = ei[e];
        const int d = ei[nE + e];
        if constexpr (C == 128) {
            const float2 v = *(const float2*)(src_feat + (size_t)s * 128 + lane * 2);
            float* o = dst_feat + (size_t)d * 128 + lane * 2;
            atomAddF(o, v.x);
            atomAddF(o + 1, v.y);
        } else {
            atomAddF(dst_feat + (size_t)d * 64 + lane,
                     src_feat[(size_t)s * 64 + lane]);
        }
    }
}

// ---------------------------------------------------------------------------
// Column stats: per-channel sum and sumsq via grid-stride + atomics.
// Requires (gridDim*blockDim) % C == 0 so each thread stays on one channel.
// ---------------------------------------------------------------------------
__global__ __launch_bounds__(256) void colstats_k(
    const float* __restrict__ buf, size_t n, int C,
    float* __restrict__ sum, float* __restrict__ sumsq)
{
    const size_t gid    = (size_t)blockIdx.x * blockDim.x + threadIdx.x;
    const size_t stride = (size_t)gridDim.x * blockDim.x;
    float s = 0.f, q = 0.f;
    for (size_t i = gid; i < n; i += stride) {
        const float v = buf[i];
        s += v;
        q += v * v;
    }
    const int c = (int)(gid % (size_t)C);
    atomAddF(&sum[c], s);
    atomAddF(&sumsq[c], q);
}

__global__ void bnfinal_k(const float* __restrict__ sum,
                          const float* __restrict__ sumsq,
                          const float* __restrict__ g,
                          const float* __restrict__ be,
                          float* __restrict__ sc, float* __restrict__ sh,
                          int C, float invN)
{
    const int c = threadIdx.x;
    if (c < C) {
        const float m = sum[c] * invN;
        const float v = sumsq[c] * invN - m * m;
        const float r = rsqrtf(v + 1e-5f);
        const float s = g[c] * r;
        sc[c] = s;
        sh[c] = be[c] - m * s;
    }
}

// ---------------------------------------------------------------------------
// In-place row log_softmax over 64 channels; one wave per row.
// ---------------------------------------------------------------------------
__global__ __launch_bounds__(256) void logsoftmax64_k(float* __restrict__ io, int M)
{
    const int w    = (blockIdx.x * blockDim.x + threadIdx.x) >> 6;
    const int lane = threadIdx.x & 63;
    const int nw   = (gridDim.x * blockDim.x) >> 6;
    for (int r = w; r < M; r += nw) {
        const float v = io[(size_t)r * 64 + lane];
        float m = v;
        for (int off = 32; off; off >>= 1) m = fmaxf(m, __shfl_xor(m, off, 64));
        float s = __expf(v - m);
        for (int off = 32; off; off >>= 1) s += __shfl_xor(s, off, 64);
        io[(size_t)r * 64 + lane] = v - m - logf(s);
    }
}

extern "C" void kernel_launch(void* const* d_in, const int* in_sizes, int n_in,
                              void* d_out, int out_size, void* d_ws, size_t ws_size,
                              hipStream_t stream)
{
    const float* x   = (const float*)d_in[0];
    const int*   ei  = (const int*)d_in[1];
    const float* w1a = (const float*)d_in[2];
    // d_in[3] = b1a: cancelled by BN mean subtraction
    const float* g1  = (const float*)d_in[4];
    const float* be1 = (const float*)d_in[5];
    const float* w1b = (const float*)d_in[6];
    const float* b1b = (const float*)d_in[7];
    const float* w2a = (const float*)d_in[8];
    // d_in[9] = b2a: cancelled by BN
    const float* g2  = (const float*)d_in[10];
    const float* be2 = (const float*)d_in[11];
    const float* w2b = (const float*)d_in[12];
    const float* b2b = (const float*)d_in[13];
    float* out = (float*)d_out;

    const int N = in_sizes[0] / 128;   // 50000
    const int E = in_sizes[1] / 2;     // 800000

    float* bufA  = (float*)d_ws;                 // N*128 : p1, then h1
    float* bufB  = bufA + (size_t)N * 128;       // N*128 : s1, then p2|s2
    float* stats = bufB + (size_t)N * 128;
    float* sum1 = stats,       *sq1 = stats + 128;
    float* sum2 = stats + 256, *sq2 = stats + 320;
    float* sc1  = stats + 384, *sh1 = stats + 512;
    float* sc2  = stats + 640, *sh2 = stats + 704;
    float* p2 = bufB;                  // N*64
    float* s2 = bufB + (size_t)N * 64; // N*64

    hipMemsetAsync(stats, 0, 384 * sizeof(float), stream);

    const int gb = (N + 63) / 64;

    // Layer 1
    gemm_tile<128, 128, false, false, false, true>
        <<<gb, 256, 0, stream>>>(x, w1a, nullptr, nullptr, nullptr, bufA, bufB, N);
    scatter_add_k<128><<<4096, 256, 0, stream>>>(bufA, bufB, ei, E);
    colstats_k<<<1024, 256, 0, stream>>>(bufB, (size_t)N * 128, 128, sum1, sq1);
    bnfinal_k<<<1, 128, 0, stream>>>(sum1, sq1, g1, be1, sc1, sh1, 128, 1.f / N);
    gemm_tile<128, 128, true, true, true, false>
        <<<gb, 256, 0, stream>>>(bufB, w1b, sc1, sh1, b1b, bufA, nullptr, N);

    // Layer 2 (aggregate AFTER projecting to 64ch: halves scatter traffic)
    gemm_tile<128, 64, false, false, false, true>
        <<<gb, 256, 0, stream>>>(bufA, w2a, nullptr, nullptr, nullptr, p2, s2, N);
    scatter_add_k<64><<<4096, 256, 0, stream>>>(p2, s2, ei, E);
    colstats_k<<<1024, 256, 0, stream>>>(s2, (size_t)N * 64, 64, sum2, sq2);
    bnfinal_k<<<1, 64, 0, stream>>>(sum2, sq2, g2, be2, sc2, sh2, 64, 1.f / N);
    gemm_tile<64, 64, true, true, false, false>
        <<<gb, 256, 0, stream>>>(s2, w2b, sc2, sh2, b2b, out, nullptr, N);
    logsoftmax64_k<<<4096, 256, 0, stream>>>(out, N);
}

// Round 2
// 551.819 us; speedup vs baseline: 1.9979x; 1.9979x over previous
//
#include <hip/hip_runtime.h>

// ---------------------------------------------------------------------------
// GIN 2-layer forward:
//   p1 = x @ w1a                                  [b1a cancels in BN]
//   CSR bucket edges by dst (hist -> scan -> fill), reused by both layers
//   s1[n] = p1[n] + sum_{e: dst=n} p1[src[e]]     (gather segment-sum)
//   stats1 -> BN affine (sc1, sh1)
//   h1 = relu( relu(sc1*s1+sh1) @ w1b + b1b )
//   p2 = h1 @ w2a                                 [b2a cancels in BN]
//   s2[n] = p2[n] + gather-sum
//   stats2 -> sc2, sh2
//   logits = relu(sc2*s2+sh2) @ w2b + b2b -> d_out ; row log_softmax in place
// ---------------------------------------------------------------------------

#define DEV_INLINE __device__ __forceinline__

DEV_INLINE void atomAddF(float* p, float v) { unsafeAtomicAdd(p, v); }

// ---------------------------------------------------------------------------
// Tiled fp32 GEMM: out[M][NC] = f(A[M][KDIM]) @ W[KDIM][NC] (+bias)(+relu)
// f = identity or per-channel BN+ReLU: relu(sc[k]*v + sh[k])
// TM=64 rows per block, 256 threads.
// ---------------------------------------------------------------------------
template <int KDIM, int NC, bool BNIN, bool BIAS, bool RELUOUT>
__global__ __launch_bounds__(256) void gemm_tile(
    const float* __restrict__ A, const float* __restrict__ W,
    const float* __restrict__ sc, const float* __restrict__ sh,
    const float* __restrict__ bias,
    float* __restrict__ out0, int M)
{
    constexpr int TM = 64, KC = 16;
    constexpr int CGRP = NC / 4;           // threads spanning the N dim
    constexpr int RT   = TM / (256 / CGRP);// rows per thread
    __shared__ float As[KC][TM + 4];       // transposed A chunk
    __shared__ float Bs[KC][NC + 4];

    const int t = threadIdx.x;
    const int block_row = blockIdx.x * TM;
    const int c0 = (t % CGRP) * 4;
    const int r0 = (t / CGRP) * RT;

    float acc[RT][4];
#pragma unroll
    for (int i = 0; i < RT; i++)
#pragma unroll
        for (int j = 0; j < 4; j++) acc[i][j] = 0.f;

    for (int kk = 0; kk < KDIM; kk += KC) {
        // ---- stage A (64 rows x 16 k), transposed, optional BN+ReLU ----
        {
            const int ar = t >> 2;
            const int ak = (t & 3) * 4;
            const int gr = block_row + ar;
            float4 v = make_float4(0.f, 0.f, 0.f, 0.f);
            if (gr < M) v = *(const float4*)(A + (size_t)gr * KDIM + kk + ak);
            if constexpr (BNIN) {
                float4 s4 = *(const float4*)(sc + kk + ak);
                float4 h4 = *(const float4*)(sh + kk + ak);
                v.x = fmaxf(0.f, v.x * s4.x + h4.x);
                v.y = fmaxf(0.f, v.y * s4.y + h4.y);
                v.z = fmaxf(0.f, v.z * s4.z + h4.z);
                v.w = fmaxf(0.f, v.w * s4.w + h4.w);
            }
            As[ak + 0][ar] = v.x;
            As[ak + 1][ar] = v.y;
            As[ak + 2][ar] = v.z;
            As[ak + 3][ar] = v.w;
        }
        // ---- stage B (16 k x NC) ----
        {
            constexpr int F4 = KC * NC / 4;
#pragma unroll
            for (int f = t; f < F4; f += 256) {
                const int bk = f / (NC / 4);
                const int bc = (f % (NC / 4)) * 4;
                *(float4*)&Bs[bk][bc] =
                    *(const float4*)(W + (size_t)(kk + bk) * NC + bc);
            }
        }
        __syncthreads();

#pragma unroll
        for (int k = 0; k < KC; k++) {
            const float4 b = *(const float4*)&Bs[k][c0];
#pragma unroll
            for (int i4 = 0; i4 < RT / 4; i4++) {
                const float4 a4 = *(const float4*)&As[k][r0 + i4 * 4];
                const float av[4] = {a4.x, a4.y, a4.z, a4.w};
#pragma unroll
                for (int j = 0; j < 4; j++) {
                    acc[i4 * 4 + j][0] += av[j] * b.x;
                    acc[i4 * 4 + j][1] += av[j] * b.y;
                    acc[i4 * 4 + j][2] += av[j] * b.z;
                    acc[i4 * 4 + j][3] += av[j] * b.w;
                }
            }
        }
        __syncthreads();
    }

    // ---- epilogue ----
    float4 bv = make_float4(0.f, 0.f, 0.f, 0.f);
    if constexpr (BIAS) bv = *(const float4*)(bias + c0);
#pragma unroll
    for (int i = 0; i < RT; i++) {
        const int gr = block_row + r0 + i;
        if (gr < M) {
            float4 o = make_float4(acc[i][0] + bv.x, acc[i][1] + bv.y,
                                   acc[i][2] + bv.z, acc[i][3] + bv.w);
            if constexpr (RELUOUT) {
                o.x = fmaxf(o.x, 0.f);
                o.y = fmaxf(o.y, 0.f);
                o.z = fmaxf(o.z, 0.f);
                o.w = fmaxf(o.w, 0.f);
            }
            *(float4*)(out0 + (size_t)gr * NC + c0) = o;
        }
    }
}

// ---------------------------------------------------------------------------
// CSR build: histogram of dst, exclusive scan, bucket fill (stores src ids).
// ---------------------------------------------------------------------------
__global__ __launch_bounds__(256) void hist_k(const int* __restrict__ ei,
                                              int* __restrict__ cnt, int E)
{
    const int gid = blockIdx.x * blockDim.x + threadIdx.x;
    const int stride = gridDim.x * blockDim.x;
    for (int e = gid; e < E; e += stride) atomicAdd(&cnt[ei[E + e]], 1);
}

// single workgroup of 1024 threads; writes off[0..N] and cursor[0..N-1]
__global__ __launch_bounds__(1024) void scan_k(const int* __restrict__ cnt,
                                               int* __restrict__ off,
                                               int* __restrict__ cursor,
                                               int N, int E)
{
    __shared__ int part[1024];
    const int t = threadIdx.x;
    const int chunk = (N + 1023) / 1024;
    const int lo = min(t * chunk, N);
    const int hi = min(lo + chunk, N);
    int s = 0;
    for (int i = lo; i < hi; i++) s += cnt[i];
    part[t] = s;
    __syncthreads();
    for (int d = 1; d < 1024; d <<= 1) {
        int u = (t >= d) ? part[t - d] : 0;
        __syncthreads();
        part[t] += u;
        __syncthreads();
    }
    int running = (t == 0) ? 0 : part[t - 1];
    for (int i = lo; i < hi; i++) {
        off[i] = running;
        cursor[i] = running;
        running += cnt[i];
    }
    if (t == 0) off[N] = E;
}

__global__ __launch_bounds__(256) void fill_k(const int* __restrict__ ei,
                                              int* __restrict__ cursor,
                                              int* __restrict__ srcs, int E)
{
    const int gid = blockIdx.x * blockDim.x + threadIdx.x;
    const int stride = gridDim.x * blockDim.x;
    for (int e = gid; e < E; e += stride) {
        const int s = ei[e];
        const int d = ei[E + e];
        const int pos = atomicAdd(&cursor[d], 1);
        srcs[pos] = s;
    }
}

// ---------------------------------------------------------------------------
// Gather segment-sum: out[n] = p[n] + sum_{e in bucket(n)} p[srcs[e]]
// One block of C threads per node; thread = channel.
// ---------------------------------------------------------------------------
template <int C>
__global__ __launch_bounds__(C) void segsum_k(
    const float* __restrict__ p, const int* __restrict__ off,
    const int* __restrict__ srcs, float* __restrict__ out, int N)
{
    const int n = blockIdx.x;
    const int c = threadIdx.x;
    const int lo = off[n], hi = off[n + 1];
    float acc = p[(size_t)n * C + c];
    int e = lo;
    for (; e + 3 < hi; e += 4) {
        const int s0 = srcs[e], s1 = srcs[e + 1], s2 = srcs[e + 2], s3 = srcs[e + 3];
        const float v0 = p[(size_t)s0 * C + c];
        const float v1 = p[(size_t)s1 * C + c];
        const float v2 = p[(size_t)s2 * C + c];
        const float v3 = p[(size_t)s3 * C + c];
        acc += v0; acc += v1; acc += v2; acc += v3;
    }
    for (; e < hi; e++) acc += p[(size_t)srcs[e] * C + c];
    out[(size_t)n * C + c] = acc;
}

// ---------------------------------------------------------------------------
// Column stats: per-channel sum and sumsq via grid-stride + atomics.
// ---------------------------------------------------------------------------
__global__ __launch_bounds__(256) void colstats_k(
    const float* __restrict__ buf, size_t n, int C,
    float* __restrict__ sum, float* __restrict__ sumsq)
{
    const size_t gid    = (size_t)blockIdx.x * blockDim.x + threadIdx.x;
    const size_t stride = (size_t)gridDim.x * blockDim.x;
    float s = 0.f, q = 0.f;
    for (size_t i = gid; i < n; i += stride) {
        const float v = buf[i];
        s += v;
        q += v * v;
    }
    const int c = (int)(gid % (size_t)C);
    atomAddF(&sum[c], s);
    atomAddF(&sumsq[c], q);
}

__global__ void bnfinal_k(const float* __restrict__ sum,
                          const float* __restrict__ sumsq,
                          const float* __restrict__ g,
                          const float* __restrict__ be,
                          float* __restrict__ sc, float* __restrict__ sh,
                          int C, float invN)
{
    const int c = threadIdx.x;
    if (c < C) {
        const float m = sum[c] * invN;
        const float v = sumsq[c] * invN - m * m;
        const float r = rsqrtf(v + 1e-5f);
        const float s = g[c] * r;
        sc[c] = s;
        sh[c] = be[c] - m * s;
    }
}

// ---------------------------------------------------------------------------
// In-place row log_softmax over 64 channels; one wave per row.
// ---------------------------------------------------------------------------
__global__ __launch_bounds__(256) void logsoftmax64_k(float* __restrict__ io, int M)
{
    const int w    = (blockIdx.x * blockDim.x + threadIdx.x) >> 6;
    const int lane = threadIdx.x & 63;
    const int nw   = (gridDim.x * blockDim.x) >> 6;
    for (int r = w; r < M; r += nw) {
        const float v = io[(size_t)r * 64 + lane];
        float m = v;
        for (int off = 32; off; off >>= 1) m = fmaxf(m, __shfl_xor(m, off, 64));
        float s = __expf(v - m);
        for (int off = 32; off; off >>= 1) s += __shfl_xor(s, off, 64);
        io[(size_t)r * 64 + lane] = v - m - logf(s);
    }
}

extern "C" void kernel_launch(void* const* d_in, const int* in_sizes, int n_in,
                              void* d_out, int out_size, void* d_ws, size_t ws_size,
                              hipStream_t stream)
{
    const float* x   = (const float*)d_in[0];
    const int*   ei  = (const int*)d_in[1];
    const float* w1a = (const float*)d_in[2];
    // d_in[3] = b1a: cancelled by BN mean subtraction
    const float* g1  = (const float*)d_in[4];
    const float* be1 = (const float*)d_in[5];
    const float* w1b = (const float*)d_in[6];
    const float* b1b = (const float*)d_in[7];
    const float* w2a = (const float*)d_in[8];
    // d_in[9] = b2a: cancelled by BN
    const float* g2  = (const float*)d_in[10];
    const float* be2 = (const float*)d_in[11];
    const float* w2b = (const float*)d_in[12];
    const float* b2b = (const float*)d_in[13];
    float* out = (float*)d_out;

    const int N = in_sizes[0] / 128;   // 50000
    const int E = in_sizes[1] / 2;     // 800000

    float* bufA  = (float*)d_ws;                 // N*128 : p1, then h1
    float* bufB  = bufA + (size_t)N * 128;       // N*128 : s1 | p2,s2
    float* stats = bufB + (size_t)N * 128;       // 1024 floats
    float* sum1 = stats,       *sq1 = stats + 128;
    float* sum2 = stats + 256, *sq2 = stats + 320;
    float* sc1  = stats + 384, *sh1 = stats + 512;
    float* sc2  = stats + 640, *sh2 = stats + 704;
    int* cnt    = (int*)(stats + 1024);          // N ints (histogram)
    int* off    = cnt + N;                       // N+1 ints
    int* cursor = off + N + 1;                   // N ints
    int* srcs   = cursor + N;                    // E ints
    float* p2 = bufB;                  // N*64
    float* s2 = bufB + (size_t)N * 64; // N*64

    hipMemsetAsync(stats, 0, 1024 * sizeof(float) + (size_t)N * sizeof(int), stream);

    const int gb = (N + 63) / 64;

    // ---- CSR build (shared by both layers) ----
    hist_k<<<1024, 256, 0, stream>>>(ei, cnt, E);
    scan_k<<<1, 1024, 0, stream>>>(cnt, off, cursor, N, E);
    fill_k<<<1024, 256, 0, stream>>>(ei, cursor, srcs, E);

    // ---- Layer 1 ----
    gemm_tile<128, 128, false, false, false>
        <<<gb, 256, 0, stream>>>(x, w1a, nullptr, nullptr, nullptr, bufA, N);
    segsum_k<128><<<N, 128, 0, stream>>>(bufA, off, srcs, bufB, N);
    colstats_k<<<1024, 256, 0, stream>>>(bufB, (size_t)N * 128, 128, sum1, sq1);
    bnfinal_k<<<1, 128, 0, stream>>>(sum1, sq1, g1, be1, sc1, sh1, 128, 1.f / N);
    gemm_tile<128, 128, true, true, true>
        <<<gb, 256, 0, stream>>>(bufB, w1b, sc1, sh1, b1b, bufA, N);

    // ---- Layer 2 (aggregate AFTER projecting to 64ch) ----
    gemm_tile<128, 64, false, false, false>
        <<<gb, 256, 0, stream>>>(bufA, w2a, nullptr, nullptr, nullptr, p2, N);
    segsum_k<64><<<N, 64, 0, stream>>>(p2, off, srcs, s2, N);
    colstats_k<<<1024, 256, 0, stream>>>(s2, (size_t)N * 64, 64, sum2, sq2);
    bnfinal_k<<<1, 64, 0, stream>>>(sum2, sq2, g2, be2, sc2, sh2, 64, 1.f / N);
    gemm_tile<64, 64, true, true, false>
        <<<gb, 256, 0, stream>>>(s2, w2b, sc2, sh2, b2b, out, N);
    logsoftmax64_k<<<4096, 256, 0, stream>>>(out, N);
}

// Round 3
// 374.314 us; speedup vs baseline: 2.9453x; 1.4742x over previous
//
#include <hip/hip_runtime.h>

// ---------------------------------------------------------------------------
// GIN 2-layer forward (MFMA bf16 GEMMs, CSR gather segment-sum):
//   CSR bucket edges by dst (hist -> 3-kernel parallel scan -> fill)
//   p1 = x @ w1a                (bf16 MFMA; b1a cancels in BN)
//   s1 = p1 + gather-sum        (fused column stats -> BN affine sc1,sh1)
//   h1 = relu( relu(sc1*s1+sh1) @ w1b + b1b )
//   p2 = h1 @ w2a               (b2a cancels in BN)
//   s2 = p2 + gather-sum        (fused stats -> sc2,sh2)
//   out = log_softmax( relu(sc2*s2+sh2) @ w2b + b2b )   (fused epilogue)
// ---------------------------------------------------------------------------

typedef unsigned short u16;
typedef __attribute__((ext_vector_type(8))) short short8;
typedef __attribute__((ext_vector_type(4))) float f32x4;

#define DEV_INLINE __device__ __forceinline__

DEV_INLINE void atomAddF(float* p, float v) { unsafeAtomicAdd(p, v); }

DEV_INLINE u16 f2bf(float f) {
    unsigned u = __float_as_uint(f);
    u += 0x7fffu + ((u >> 16) & 1u);   // round-to-nearest-even
    return (u16)(u >> 16);
}

// ---------------------------------------------------------------------------
// Weight prep: W[K][NOUT] fp32 -> frag-ordered bf16.
// unit = (ct, kc, lane): holds 8 bf16 for col = ct*16+(lane&15),
// k = kc*32 + (lane>>4)*8 + j. Used as the MFMA A-operand (swapped scheme).
// ---------------------------------------------------------------------------
__global__ __launch_bounds__(256) void wprep_k(const float* __restrict__ W,
                                               short* __restrict__ wf,
                                               int K, int NOUT)
{
    const int units = (NOUT / 16) * (K / 32) * 64;
    const int u = blockIdx.x * 256 + threadIdx.x;
    if (u >= units) return;
    const int per_ct = (K / 32) * 64;
    const int ct = u / per_ct;
    const int rem = u % per_ct;
    const int kc = rem >> 6;
    const int l = rem & 63;
    const int col = ct * 16 + (l & 15);
    const int k0 = kc * 32 + (l >> 4) * 8;
    short8 pk;
#pragma unroll
    for (int j = 0; j < 8; j++)
        pk[j] = (short)f2bf(W[(size_t)(k0 + j) * NOUT + col]);
    *(short8*)&wf[(size_t)u * 8] = pk;
}

// ---------------------------------------------------------------------------
// MFMA GEMM (swapped operands => per-lane float4 C-writes):
//   out[M][NC] = f(A[M][KD]) @ W   (+bias) (+relu | +row log_softmax)
// f = identity or BN+ReLU: relu(sc[k]*v + sh[k]).
// BM=128 rows/block, 256 threads (4 waves), full K resident in LDS.
// ---------------------------------------------------------------------------
template <int KD, int NC, bool BNIN, bool BIAS, bool RELUOUT, bool LOGSM>
__global__ __launch_bounds__(256) void mgemm(
    const float* __restrict__ A, const short* __restrict__ Wf,
    const float* __restrict__ sc, const float* __restrict__ sh,
    const float* __restrict__ bias, float* __restrict__ out, int M)
{
    constexpr int BM = 128;
    constexpr int KC = KD / 32;   // 32-wide k chunks
    constexpr int CT = NC / 16;   // 16-wide col tiles
    __shared__ short Asl[BM * KD];
    __shared__ short Bsl[NC * KD];

    const int t = threadIdx.x;
    const int l = t & 63;
    const int w = t >> 6;

    // ---- stage B: frag-ordered weights, linear copy ----
    {
        const float4* src = (const float4*)Wf;
        float4* dst = (float4*)Bsl;
        constexpr int NU = NC * KD / 8;
#pragma unroll
        for (int u = t; u < NU; u += 256) dst[u] = src[u];
    }
    // ---- stage A: 2 threads per row, fp32 load -> (BN+ReLU) -> bf16 frags ----
    {
        const int r = t >> 1;
        const int half = t & 1;
        const int grow = blockIdx.x * BM + r;
        const int rt = r >> 4;
        constexpr int KH = KD / 2;
        float vals[KH];
        if (grow < M) {
            const float* ap = A + (size_t)grow * KD + half * KH;
#pragma unroll
            for (int i = 0; i < KH / 4; i++) {
                const float4 v = ((const float4*)ap)[i];
                vals[i * 4 + 0] = v.x; vals[i * 4 + 1] = v.y;
                vals[i * 4 + 2] = v.z; vals[i * 4 + 3] = v.w;
            }
            if constexpr (BNIN) {
#pragma unroll
                for (int i = 0; i < KH; i++) {
                    const int k = half * KH + i;
                    vals[i] = fmaxf(0.f, vals[i] * sc[k] + sh[k]);
                }
            }
        } else {
#pragma unroll
            for (int i = 0; i < KH; i++) vals[i] = 0.f;
        }
#pragma unroll
        for (int g = 0; g < KH / 8; g++) {
            const int k0 = half * KH + g * 8;
            const int kc = k0 >> 5;
            const int lane = (r & 15) + ((k0 >> 3) & 3) * 16;
            short8 pk;
#pragma unroll
            for (int j = 0; j < 8; j++) pk[j] = (short)f2bf(vals[g * 8 + j]);
            *(short8*)&Asl[((rt * KC + kc) * 64 + lane) * 8] = pk;
        }
    }
    __syncthreads();

    // ---- MFMA: wave w owns row-tiles {2w, 2w+1} x all col-tiles ----
    const int rt0 = w * 2;
    f32x4 acc[2][CT];
#pragma unroll
    for (int i = 0; i < 2; i++)
#pragma unroll
        for (int c = 0; c < CT; c++) acc[i][c] = (f32x4){0.f, 0.f, 0.f, 0.f};

#pragma unroll
    for (int kc = 0; kc < KC; kc++) {
        const short8 x0 = *(const short8*)&Asl[((rt0 * KC + kc) * 64 + l) * 8];
        const short8 x1 = *(const short8*)&Asl[(((rt0 + 1) * KC + kc) * 64 + l) * 8];
#pragma unroll
        for (int ct = 0; ct < CT; ct++) {
            const short8 wb = *(const short8*)&Bsl[((ct * KC + kc) * 64 + l) * 8];
            acc[0][ct] = __builtin_amdgcn_mfma_f32_16x16x32_bf16(wb, x0, acc[0][ct], 0, 0, 0);
            acc[1][ct] = __builtin_amdgcn_mfma_f32_16x16x32_bf16(wb, x1, acc[1][ct], 0, 0, 0);
        }
    }

    // ---- epilogue: lane l holds row (l&15) of tile, cols (l>>4)*4+{0..3} ----
    const int cbase = (l >> 4) * 4;
#pragma unroll
    for (int rr = 0; rr < 2; rr++) {
        const int grow = blockIdx.x * BM + (rt0 + rr) * 16 + (l & 15);
        if constexpr (!LOGSM) {
            if (grow < M) {
#pragma unroll
                for (int ct = 0; ct < CT; ct++) {
                    f32x4 o = acc[rr][ct];
                    if constexpr (BIAS) {
                        const float4 bv = *(const float4*)&bias[ct * 16 + cbase];
                        o[0] += bv.x; o[1] += bv.y; o[2] += bv.z; o[3] += bv.w;
                    }
                    if constexpr (RELUOUT) {
#pragma unroll
                        for (int j = 0; j < 4; j++) o[j] = fmaxf(o[j], 0.f);
                    }
                    *(f32x4*)&out[(size_t)grow * NC + ct * 16 + cbase] = o;
                }
            }
        } else {
            // fused row log_softmax (row spread across lanes l, l^16, l^32, l^48)
            float v[CT * 4];
#pragma unroll
            for (int ct = 0; ct < CT; ct++) {
                const float4 bv = *(const float4*)&bias[ct * 16 + cbase];
                v[ct * 4 + 0] = acc[rr][ct][0] + bv.x;
                v[ct * 4 + 1] = acc[rr][ct][1] + bv.y;
                v[ct * 4 + 2] = acc[rr][ct][2] + bv.z;
                v[ct * 4 + 3] = acc[rr][ct][3] + bv.w;
            }
            float m = v[0];
#pragma unroll
            for (int j = 1; j < CT * 4; j++) m = fmaxf(m, v[j]);
            m = fmaxf(m, __shfl_xor(m, 16));
            m = fmaxf(m, __shfl_xor(m, 32));
            float s = 0.f;
#pragma unroll
            for (int j = 0; j < CT * 4; j++) s += __expf(v[j] - m);
            s += __shfl_xor(s, 16);
            s += __shfl_xor(s, 32);
            const float lg = m + __logf(s);
            if (grow < M) {
#pragma unroll
                for (int ct = 0; ct < CT; ct++) {
                    f32x4 o;
#pragma unroll
                    for (int j = 0; j < 4; j++) o[j] = v[ct * 4 + j] - lg;
                    *(f32x4*)&out[(size_t)grow * NC + ct * 16 + cbase] = o;
                }
            }
        }
    }
}

// ---------------------------------------------------------------------------
// CSR build: histogram, 3-kernel parallel exclusive scan, bucket fill.
// ---------------------------------------------------------------------------
__global__ __launch_bounds__(256) void hist_k(const int* __restrict__ ei,
                                              int* __restrict__ cnt, int E)
{
    const int gid = blockIdx.x * blockDim.x + threadIdx.x;
    const int stride = gridDim.x * blockDim.x;
    for (int e = gid; e < E; e += stride) atomicAdd(&cnt[ei[E + e]], 1);
}

__global__ __launch_bounds__(256) void bsum_k(const int* __restrict__ cnt,
                                              int* __restrict__ bsum, int N)
{
    __shared__ int ws[4];
    const int i = blockIdx.x * 256 + threadIdx.x;
    int v = (i < N) ? cnt[i] : 0;
    for (int d = 32; d; d >>= 1) v += __shfl_xor(v, d, 64);
    if ((threadIdx.x & 63) == 0) ws[threadIdx.x >> 6] = v;
    __syncthreads();
    if (threadIdx.x == 0) bsum[blockIdx.x] = ws[0] + ws[1] + ws[2] + ws[3];
}

// single block; G1 <= 256
__global__ __launch_bounds__(256) void bscan_k(const int* __restrict__ bsum,
                                               int* __restrict__ bpre, int G1)
{
    __shared__ int part[256];
    const int t = threadIdx.x;
    const int v = (t < G1) ? bsum[t] : 0;
    part[t] = v;
    __syncthreads();
    for (int d = 1; d < 256; d <<= 1) {
        const int u = (t >= d) ? part[t - d] : 0;
        __syncthreads();
        part[t] += u;
        __syncthreads();
    }
    bpre[t] = part[t] - v;   // exclusive
}

__global__ __launch_bounds__(256) void offs_k(const int* __restrict__ cnt,
                                              const int* __restrict__ bpre,
                                              int* __restrict__ off,
                                              int* __restrict__ cursor,
                                              int N, int E)
{
    __shared__ int part[256];
    const int t = threadIdx.x;
    const int i = blockIdx.x * 256 + t;
    const int v = (i < N) ? cnt[i] : 0;
    part[t] = v;
    __syncthreads();
    for (int d = 1; d < 256; d <<= 1) {
        const int u = (t >= d) ? part[t - d] : 0;
        __syncthreads();
        part[t] += u;
        __syncthreads();
    }
    if (i < N) {
        const int o = bpre[blockIdx.x] + part[t] - v;
        off[i] = o;
        cursor[i] = o;
    }
    if (blockIdx.x == 0 && t == 0) off[N] = E;
}

__global__ __launch_bounds__(256) void fill_k(const int* __restrict__ ei,
                                              int* __restrict__ cursor,
                                              int* __restrict__ srcs, int E)
{
    const int gid = blockIdx.x * blockDim.x + threadIdx.x;
    const int stride = gridDim.x * blockDim.x;
    for (int e = gid; e < E; e += stride) {
        const int s = ei[e];
        const int d = ei[E + e];
        const int pos = atomicAdd(&cursor[d], 1);
        srcs[pos] = s;
    }
}

// ---------------------------------------------------------------------------
// Gather segment-sum + fused column stats.
// Block = C threads (thread=channel), BLKN nodes per block.
// ---------------------------------------------------------------------------
template <int C>
__global__ __launch_bounds__(C) void segsum_k(
    const float* __restrict__ p, const int* __restrict__ off,
    const int* __restrict__ srcs, float* __restrict__ out,
    float* __restrict__ sum, float* __restrict__ sumsq, int N)
{
    constexpr int BLKN = 32;
    const int c = threadIdx.x;
    const int n0 = blockIdx.x * BLKN;
    const int n1 = min(n0 + BLKN, N);
    float ssum = 0.f, ssq = 0.f;
    for (int n = n0; n < n1; n++) {
        const int lo = off[n], hi = off[n + 1];
        float acc = p[(size_t)n * C + c];
        int e = lo;
        for (; e + 3 < hi; e += 4) {
            const int s0 = srcs[e], s1 = srcs[e + 1];
            const int s2 = srcs[e + 2], s3 = srcs[e + 3];
            acc += p[(size_t)s0 * C + c];
            acc += p[(size_t)s1 * C + c];
            acc += p[(size_t)s2 * C + c];
            acc += p[(size_t)s3 * C + c];
        }
        for (; e < hi; e++) acc += p[(size_t)srcs[e] * C + c];
        out[(size_t)n * C + c] = acc;
        ssum += acc;
        ssq += acc * acc;
    }
    atomAddF(&sum[c], ssum);
    atomAddF(&sumsq[c], ssq);
}

__global__ void bnfinal_k(const float* __restrict__ sum,
                          const float* __restrict__ sumsq,
                          const float* __restrict__ g,
                          const float* __restrict__ be,
                          float* __restrict__ sc, float* __restrict__ sh,
                          int C, float invN)
{
    const int c = threadIdx.x;
    if (c < C) {
        const float m = sum[c] * invN;
        const float v = sumsq[c] * invN - m * m;
        const float r = rsqrtf(v + 1e-5f);
        const float s = g[c] * r;
        sc[c] = s;
        sh[c] = be[c] - m * s;
    }
}

extern "C" void kernel_launch(void* const* d_in, const int* in_sizes, int n_in,
                              void* d_out, int out_size, void* d_ws, size_t ws_size,
                              hipStream_t stream)
{
    const float* x   = (const float*)d_in[0];
    const int*   ei  = (const int*)d_in[1];
    const float* w1a = (const float*)d_in[2];
    // d_in[3] = b1a: cancelled by BN
    const float* g1  = (const float*)d_in[4];
    const float* be1 = (const float*)d_in[5];
    const float* w1b = (const float*)d_in[6];
    const float* b1b = (const float*)d_in[7];
    const float* w2a = (const float*)d_in[8];
    // d_in[9] = b2a: cancelled by BN
    const float* g2  = (const float*)d_in[10];
    const float* be2 = (const float*)d_in[11];
    const float* w2b = (const float*)d_in[12];
    const float* b2b = (const float*)d_in[13];
    float* out = (float*)d_out;

    const int N = in_sizes[0] / 128;   // 50000
    const int E = in_sizes[1] / 2;     // 800000

    // ---- workspace layout (floats unless noted) ----
    float* bufA  = (float*)d_ws;                 // N*128 : p1, then h1
    float* bufB  = bufA + (size_t)N * 128;       // N*128 : s1 | p2,s2
    float* stats = bufB + (size_t)N * 128;       // 1024
    float* sum1 = stats,       *sq1 = stats + 128;
    float* sum2 = stats + 256, *sq2 = stats + 320;
    float* sc1  = stats + 384, *sh1 = stats + 512;
    float* sc2  = stats + 640, *sh2 = stats + 704;
    int* cnt    = (int*)(stats + 1024);          // N
    int* off    = cnt + N;                       // N+1
    int* cursor = off + N + 1;                   // N
    int* srcs   = cursor + N;                    // E
    int* bsum   = srcs + E;                      // 256
    int* bpre   = bsum + 256;                    // 256
    // bf16 frag-ordered weights (16B aligned: everything above is 4B units,
    // total offset is a multiple of 4 floats)
    short* w1af = (short*)(bpre + 256);          // 128*128
    short* w1bf = w1af + 128 * 128;              // 128*128
    short* w2af = w1bf + 128 * 128;              // 128*64
    short* w2bf = w2af + 128 * 64;               // 64*64
    float* p2 = bufB;                  // N*64
    float* s2 = bufB + (size_t)N * 64; // N*64

    hipMemsetAsync(stats, 0, 1024 * sizeof(float) + (size_t)N * sizeof(int), stream);

    const int G1 = (N + 255) / 256;
    const int gb = (N + 127) / 128;
    const int gs = (N + 31) / 32;

    // ---- CSR build ----
    hist_k<<<1024, 256, 0, stream>>>(ei, cnt, E);
    bsum_k<<<G1, 256, 0, stream>>>(cnt, bsum, N);
    bscan_k<<<1, 256, 0, stream>>>(bsum, bpre, G1);
    offs_k<<<G1, 256, 0, stream>>>(cnt, bpre, off, cursor, N, E);
    fill_k<<<1024, 256, 0, stream>>>(ei, cursor, srcs, E);

    // ---- weight prep (independent of CSR) ----
    wprep_k<<<8, 256, 0, stream>>>(w1a, w1af, 128, 128);
    wprep_k<<<8, 256, 0, stream>>>(w1b, w1bf, 128, 128);
    wprep_k<<<4, 256, 0, stream>>>(w2a, w2af, 128, 64);
    wprep_k<<<2, 256, 0, stream>>>(w2b, w2bf, 64, 64);

    // ---- Layer 1 ----
    mgemm<128, 128, false, false, false, false>
        <<<gb, 256, 0, stream>>>(x, w1af, nullptr, nullptr, nullptr, bufA, N);
    segsum_k<128><<<gs, 128, 0, stream>>>(bufA, off, srcs, bufB, sum1, sq1, N);
    bnfinal_k<<<1, 128, 0, stream>>>(sum1, sq1, g1, be1, sc1, sh1, 128, 1.f / N);
    mgemm<128, 128, true, true, true, false>
        <<<gb, 256, 0, stream>>>(bufB, w1bf, sc1, sh1, b1b, bufA, N);

    // ---- Layer 2 (aggregate after projecting to 64ch) ----
    mgemm<128, 64, false, false, false, false>
        <<<gb, 256, 0, stream>>>(bufA, w2af, nullptr, nullptr, nullptr, p2, N);
    segsum_k<64><<<gs, 64, 0, stream>>>(p2, off, srcs, s2, sum2, sq2, N);
    bnfinal_k<<<1, 64, 0, stream>>>(sum2, sq2, g2, be2, sc2, sh2, 64, 1.f / N);
    mgemm<64, 64, true, true, false, true>
        <<<gb, 256, 0, stream>>>(s2, w2bf, sc2, sh2, b2b, out, N);
}

// Round 4
// 338.327 us; speedup vs baseline: 3.2586x; 1.1064x over previous
//
#include <hip/hip_runtime.h>

// ---------------------------------------------------------------------------
// GIN 2-layer forward (bf16 features everywhere, MFMA GEMMs, CSR gather):
//   CSR bucket edges by dst (hist -> parallel scan -> fill)
//   p1 = bf16( x @ w1a )                      [b1a cancels in BN]
//   s1 = bf16( p1[n] + gather-sum )           (fused column stats)
//   h1 = bf16( relu( relu(sc1*s1+sh1) @ w1b + b1b ) )
//   p2 = bf16( h1 @ w2a )                     [b2a cancels in BN]
//   s2 = bf16( p2[n] + gather-sum )           (fused stats)
//   out = log_softmax( relu(sc2*s2+sh2) @ w2b + b2b )  fp32, fused epilogue
// ---------------------------------------------------------------------------

typedef unsigned short u16;
typedef __attribute__((ext_vector_type(8))) short short8;
typedef __attribute__((ext_vector_type(4))) short short4v;
typedef __attribute__((ext_vector_type(4))) float f32x4;

#define DEV_INLINE __device__ __forceinline__

DEV_INLINE void atomAddF(float* p, float v) { unsafeAtomicAdd(p, v); }

DEV_INLINE u16 f2bf(float f) {
    unsigned u = __float_as_uint(f);
    u += 0x7fffu + ((u >> 16) & 1u);   // round-to-nearest-even
    return (u16)(u >> 16);
}
DEV_INLINE float bf2f(u16 h) { return __uint_as_float(((unsigned)h) << 16); }

// ---------------------------------------------------------------------------
// Weight prep: W[K][NOUT] fp32 -> frag-ordered bf16 (MFMA A-operand, swapped).
// unit = (ct, kc, lane): 8 bf16 for col = ct*16+(lane&15), k = kc*32+(lane>>4)*8+j.
// ---------------------------------------------------------------------------
__global__ __launch_bounds__(256) void wprep_k(const float* __restrict__ W,
                                               short* __restrict__ wf,
                                               int K, int NOUT)
{
    const int units = (NOUT / 16) * (K / 32) * 64;
    const int u = blockIdx.x * 256 + threadIdx.x;
    if (u >= units) return;
    const int per_ct = (K / 32) * 64;
    const int ct = u / per_ct;
    const int rem = u % per_ct;
    const int kc = rem >> 6;
    const int l = rem & 63;
    const int col = ct * 16 + (l & 15);
    const int k0 = kc * 32 + (l >> 4) * 8;
    short8 pk;
#pragma unroll
    for (int j = 0; j < 8; j++)
        pk[j] = (short)f2bf(W[(size_t)(k0 + j) * NOUT + col]);
    *(short8*)&wf[(size_t)u * 8] = pk;
}

// ---------------------------------------------------------------------------
// MFMA GEMM (swapped operands => per-lane contiguous C-writes):
//   out[M][NC] = f(A[M][KD]) @ W  (+bias) (+relu | +row log_softmax)
// A is fp32 or bf16; out is bf16 or fp32. BM=128 rows, 256 threads (4 waves).
// ---------------------------------------------------------------------------
template <int KD, int NC, bool ABF16, bool BNIN, bool BIAS, bool RELUOUT,
          bool LOGSM, bool OBF16>
__global__ __launch_bounds__(256) void mgemm(
    const void* __restrict__ Ap, const short* __restrict__ Wf,
    const float* __restrict__ sc, const float* __restrict__ sh,
    const float* __restrict__ bias, void* __restrict__ outp, int M)
{
    constexpr int BM = 128;
    constexpr int KC = KD / 32;   // 32-wide k chunks
    constexpr int CT = NC / 16;   // 16-wide col tiles
    __shared__ short Asl[BM * KD];
    __shared__ short Bsl[NC * KD];

    const int t = threadIdx.x;
    const int l = t & 63;
    const int w = t >> 6;

    // ---- stage B: frag-ordered weights, linear copy ----
    {
        const float4* src = (const float4*)Wf;
        float4* dst = (float4*)Bsl;
        constexpr int NU = NC * KD / 8;
#pragma unroll
        for (int u = t; u < NU; u += 256) dst[u] = src[u];
    }
    // ---- stage A: 2 threads per row -> (BN+ReLU) -> bf16 frags ----
    {
        const int r = t >> 1;
        const int half = t & 1;
        const int grow = blockIdx.x * BM + r;
        const int rt = r >> 4;
        constexpr int KH = KD / 2;
        u16 hv[KH];
        if (grow < M) {
            if constexpr (ABF16) {
                const u16* ap = (const u16*)Ap + (size_t)grow * KD + half * KH;
#pragma unroll
                for (int i = 0; i < KH / 8; i++)
                    *(short8*)&hv[i * 8] = ((const short8*)ap)[i];
                if constexpr (BNIN) {
#pragma unroll
                    for (int i = 0; i < KH; i++) {
                        const int k = half * KH + i;
                        hv[i] = f2bf(fmaxf(0.f, bf2f(hv[i]) * sc[k] + sh[k]));
                    }
                }
            } else {
                const float* ap = (const float*)Ap + (size_t)grow * KD + half * KH;
#pragma unroll
                for (int i = 0; i < KH / 4; i++) {
                    const float4 v = ((const float4*)ap)[i];
                    float f0 = v.x, f1 = v.y, f2 = v.z, f3 = v.w;
                    if constexpr (BNIN) {
                        const int k = half * KH + i * 4;
                        f0 = fmaxf(0.f, f0 * sc[k + 0] + sh[k + 0]);
                        f1 = fmaxf(0.f, f1 * sc[k + 1] + sh[k + 1]);
                        f2 = fmaxf(0.f, f2 * sc[k + 2] + sh[k + 2]);
                        f3 = fmaxf(0.f, f3 * sc[k + 3] + sh[k + 3]);
                    }
                    hv[i * 4 + 0] = f2bf(f0); hv[i * 4 + 1] = f2bf(f1);
                    hv[i * 4 + 2] = f2bf(f2); hv[i * 4 + 3] = f2bf(f3);
                }
            }
        } else {
#pragma unroll
            for (int i = 0; i < KH; i++) hv[i] = 0;
        }
#pragma unroll
        for (int g = 0; g < KH / 8; g++) {
            const int k0 = half * KH + g * 8;
            const int kc = k0 >> 5;
            const int lane = (r & 15) + ((k0 >> 3) & 3) * 16;
            *(short8*)&Asl[((rt * KC + kc) * 64 + lane) * 8] =
                *(short8*)&hv[g * 8];
        }
    }
    __syncthreads();

    // ---- MFMA: wave w owns row-tiles {2w, 2w+1} x all col-tiles ----
    const int rt0 = w * 2;
    f32x4 acc[2][CT];
#pragma unroll
    for (int i = 0; i < 2; i++)
#pragma unroll
        for (int c = 0; c < CT; c++) acc[i][c] = (f32x4){0.f, 0.f, 0.f, 0.f};

#pragma unroll
    for (int kc = 0; kc < KC; kc++) {
        const short8 x0 = *(const short8*)&Asl[((rt0 * KC + kc) * 64 + l) * 8];
        const short8 x1 = *(const short8*)&Asl[(((rt0 + 1) * KC + kc) * 64 + l) * 8];
#pragma unroll
        for (int ct = 0; ct < CT; ct++) {
            const short8 wb = *(const short8*)&Bsl[((ct * KC + kc) * 64 + l) * 8];
            acc[0][ct] = __builtin_amdgcn_mfma_f32_16x16x32_bf16(wb, x0, acc[0][ct], 0, 0, 0);
            acc[1][ct] = __builtin_amdgcn_mfma_f32_16x16x32_bf16(wb, x1, acc[1][ct], 0, 0, 0);
        }
    }

    // ---- epilogue: lane l holds row (l&15), cols (l>>4)*4+{0..3} of tile ----
    const int cbase = (l >> 4) * 4;
#pragma unroll
    for (int rr = 0; rr < 2; rr++) {
        const int grow = blockIdx.x * BM + (rt0 + rr) * 16 + (l & 15);
        if constexpr (!LOGSM) {
            if (grow < M) {
#pragma unroll
                for (int ct = 0; ct < CT; ct++) {
                    f32x4 o = acc[rr][ct];
                    if constexpr (BIAS) {
                        const float4 bv = *(const float4*)&bias[ct * 16 + cbase];
                        o[0] += bv.x; o[1] += bv.y; o[2] += bv.z; o[3] += bv.w;
                    }
                    if constexpr (RELUOUT) {
#pragma unroll
                        for (int j = 0; j < 4; j++) o[j] = fmaxf(o[j], 0.f);
                    }
                    if constexpr (OBF16) {
                        short4v o16;
#pragma unroll
                        for (int j = 0; j < 4; j++) o16[j] = (short)f2bf(o[j]);
                        *(short4v*)&((u16*)outp)[(size_t)grow * NC + ct * 16 + cbase] = o16;
                    } else {
                        *(f32x4*)&((float*)outp)[(size_t)grow * NC + ct * 16 + cbase] = o;
                    }
                }
            }
        } else {
            // fused row log_softmax (row spread across lanes l, l^16, l^32, l^48)
            float v[CT * 4];
#pragma unroll
            for (int ct = 0; ct < CT; ct++) {
                const float4 bv = *(const float4*)&bias[ct * 16 + cbase];
                v[ct * 4 + 0] = acc[rr][ct][0] + bv.x;
                v[ct * 4 + 1] = acc[rr][ct][1] + bv.y;
                v[ct * 4 + 2] = acc[rr][ct][2] + bv.z;
                v[ct * 4 + 3] = acc[rr][ct][3] + bv.w;
            }
            float m = v[0];
#pragma unroll
            for (int j = 1; j < CT * 4; j++) m = fmaxf(m, v[j]);
            m = fmaxf(m, __shfl_xor(m, 16));
            m = fmaxf(m, __shfl_xor(m, 32));
            float s = 0.f;
#pragma unroll
            for (int j = 0; j < CT * 4; j++) s += __expf(v[j] - m);
            s += __shfl_xor(s, 16);
            s += __shfl_xor(s, 32);
            const float lg = m + __logf(s);
            if (grow < M) {
#pragma unroll
                for (int ct = 0; ct < CT; ct++) {
                    f32x4 o;
#pragma unroll
                    for (int j = 0; j < 4; j++) o[j] = v[ct * 4 + j] - lg;
                    *(f32x4*)&((float*)outp)[(size_t)grow * NC + ct * 16 + cbase] = o;
                }
            }
        }
    }
}

// ---------------------------------------------------------------------------
// CSR build: histogram, 3-kernel parallel exclusive scan, bucket fill.
// ---------------------------------------------------------------------------
__global__ __launch_bounds__(256) void hist_k(const int* __restrict__ ei,
                                              int* __restrict__ cnt, int E)
{
    const int gid = blockIdx.x * blockDim.x + threadIdx.x;
    const int stride = gridDim.x * blockDim.x;
    for (int e = gid; e < E; e += stride) atomicAdd(&cnt[ei[E + e]], 1);
}

__global__ __launch_bounds__(256) void bsum_k(const int* __restrict__ cnt,
                                              int* __restrict__ bsum, int N)
{
    __shared__ int ws[4];
    const int i = blockIdx.x * 256 + threadIdx.x;
    int v = (i < N) ? cnt[i] : 0;
    for (int d = 32; d; d >>= 1) v += __shfl_xor(v, d, 64);
    if ((threadIdx.x & 63) == 0) ws[threadIdx.x >> 6] = v;
    __syncthreads();
    if (threadIdx.x == 0) bsum[blockIdx.x] = ws[0] + ws[1] + ws[2] + ws[3];
}

// single block; G1 <= 256
__global__ __launch_bounds__(256) void bscan_k(const int* __restrict__ bsum,
                                               int* __restrict__ bpre, int G1)
{
    __shared__ int part[256];
    const int t = threadIdx.x;
    const int v = (t < G1) ? bsum[t] : 0;
    part[t] = v;
    __syncthreads();
    for (int d = 1; d < 256; d <<= 1) {
        const int u = (t >= d) ? part[t - d] : 0;
        __syncthreads();
        part[t] += u;
        __syncthreads();
    }
    bpre[t] = part[t] - v;   // exclusive
}

__global__ __launch_bounds__(256) void offs_k(const int* __restrict__ cnt,
                                              const int* __restrict__ bpre,
                                              int* __restrict__ off,
                                              int* __restrict__ cursor,
                                              int N, int E)
{
    __shared__ int part[256];
    const int t = threadIdx.x;
    const int i = blockIdx.x * 256 + t;
    const int v = (i < N) ? cnt[i] : 0;
    part[t] = v;
    __syncthreads();
    for (int d = 1; d < 256; d <<= 1) {
        const int u = (t >= d) ? part[t - d] : 0;
        __syncthreads();
        part[t] += u;
        __syncthreads();
    }
    if (i < N) {
        const int o = bpre[blockIdx.x] + part[t] - v;
        off[i] = o;
        cursor[i] = o;
    }
    if (blockIdx.x == 0 && t == 0) off[N] = E;
}

__global__ __launch_bounds__(256) void fill_k(const int* __restrict__ ei,
                                              int* __restrict__ cursor,
                                              int* __restrict__ srcs, int E)
{
    const int gid = blockIdx.x * blockDim.x + threadIdx.x;
    const int stride = gridDim.x * blockDim.x;
    for (int e = gid; e < E; e += stride) {
        const int s = ei[e];
        const int d = ei[E + e];
        const int pos = atomicAdd(&cursor[d], 1);
        srcs[pos] = s;
    }
}

// ---------------------------------------------------------------------------
// Gather segment-sum (bf16 in/out) + fused column stats.
// 256 threads = NPG wave-aligned node slots; thread = channel within slot.
// ---------------------------------------------------------------------------
template <int C>
__global__ __launch_bounds__(256) void segsum_bf(
    const u16* __restrict__ p, const int* __restrict__ off,
    const int* __restrict__ srcs, u16* __restrict__ out,
    float* __restrict__ sum, float* __restrict__ sumsq, int N)
{
    constexpr int NPG  = 256 / C;   // node slots per block (wave-aligned)
    constexpr int BLKN = 16;        // nodes per slot
    __shared__ float red[256];

    const int slot = threadIdx.x / C;
    const int c = threadIdx.x % C;
    const int base = blockIdx.x * (NPG * BLKN);
    float ssum = 0.f, ssq = 0.f;

    for (int i = 0; i < BLKN; i++) {
        const int n = base + i * NPG + slot;
        if (n < N) {
            const int lo = off[n], hi = off[n + 1];
            float acc = bf2f(p[(size_t)n * C + c]);
            int e = lo;
            for (; e + 3 < hi; e += 4) {
                const int s0 = srcs[e], s1 = srcs[e + 1];
                const int s2 = srcs[e + 2], s3 = srcs[e + 3];
                const float v0 = bf2f(p[(size_t)s0 * C + c]);
                const float v1 = bf2f(p[(size_t)s1 * C + c]);
                const float v2 = bf2f(p[(size_t)s2 * C + c]);
                const float v3 = bf2f(p[(size_t)s3 * C + c]);
                acc += v0; acc += v1; acc += v2; acc += v3;
            }
            for (; e < hi; e++) acc += bf2f(p[(size_t)srcs[e] * C + c]);
            const u16 r = f2bf(acc);
            out[(size_t)n * C + c] = r;
            const float rf = bf2f(r);   // stats on the rounded value
            ssum += rf;
            ssq += rf * rf;
        }
    }
    // cross-slot reduce, then one atomic per channel per block
    if (slot > 0) red[threadIdx.x] = ssum;
    __syncthreads();
    if (slot == 0) {
#pragma unroll
        for (int s = 1; s < NPG; s++) ssum += red[s * C + c];
    }
    __syncthreads();
    if (slot > 0) red[threadIdx.x] = ssq;
    __syncthreads();
    if (slot == 0) {
#pragma unroll
        for (int s = 1; s < NPG; s++) ssq += red[s * C + c];
        atomAddF(&sum[c], ssum);
        atomAddF(&sumsq[c], ssq);
    }
}

__global__ void bnfinal_k(const float* __restrict__ sum,
                          const float* __restrict__ sumsq,
                          const float* __restrict__ g,
                          const float* __restrict__ be,
                          float* __restrict__ sc, float* __restrict__ sh,
                          int C, float invN)
{
    const int c = threadIdx.x;
    if (c < C) {
        const float m = sum[c] * invN;
        const float v = sumsq[c] * invN - m * m;
        const float r = rsqrtf(v + 1e-5f);
        const float s = g[c] * r;
        sc[c] = s;
        sh[c] = be[c] - m * s;
    }
}

extern "C" void kernel_launch(void* const* d_in, const int* in_sizes, int n_in,
                              void* d_out, int out_size, void* d_ws, size_t ws_size,
                              hipStream_t stream)
{
    const float* x   = (const float*)d_in[0];
    const int*   ei  = (const int*)d_in[1];
    const float* w1a = (const float*)d_in[2];
    // d_in[3] = b1a: cancelled by BN
    const float* g1  = (const float*)d_in[4];
    const float* be1 = (const float*)d_in[5];
    const float* w1b = (const float*)d_in[6];
    const float* b1b = (const float*)d_in[7];
    const float* w2a = (const float*)d_in[8];
    // d_in[9] = b2a: cancelled by BN
    const float* g2  = (const float*)d_in[10];
    const float* be2 = (const float*)d_in[11];
    const float* w2b = (const float*)d_in[12];
    const float* b2b = (const float*)d_in[13];
    float* out = (float*)d_out;

    const int N = in_sizes[0] / 128;   // 50000
    const int E = in_sizes[1] / 2;     // 800000

    // ---- workspace layout ----
    u16* buf1 = (u16*)d_ws;                      // N*128 bf16 : p1, then h1
    u16* buf2 = buf1 + (size_t)N * 128;          // N*128 bf16 : s1, then p2|s2
    float* stats = (float*)(buf2 + (size_t)N * 128);  // 1024 floats
    float* sum1 = stats,       *sq1 = stats + 128;
    float* sum2 = stats + 256, *sq2 = stats + 320;
    float* sc1  = stats + 384, *sh1 = stats + 512;
    float* sc2  = stats + 640, *sh2 = stats + 704;
    int* cnt    = (int*)(stats + 1024);          // N
    int* off    = cnt + N;                       // N+1
    int* cursor = off + N + 1;                   // N
    int* srcs   = cursor + N;                    // E
    int* bsum   = srcs + E;                      // 256
    int* bpre   = bsum + 256;                    // 256
    short* w1af = (short*)(bpre + 256);          // 128*128
    short* w1bf = w1af + 128 * 128;              // 128*128
    short* w2af = w1bf + 128 * 128;              // 128*64
    short* w2bf = w2af + 128 * 64;               // 64*64
    u16* p1 = buf1;
    u16* s1 = buf2;
    u16* h1 = buf1;                    // reuse: p1 dead after segsum1
    u16* p2 = buf2;                    // reuse: s1 dead after mgemm2 (N*64)
    u16* s2 = buf2 + (size_t)N * 64;   // upper half

    hipMemsetAsync(stats, 0, 1024 * sizeof(float) + (size_t)N * sizeof(int), stream);

    const int G1 = (N + 255) / 256;
    const int gb = (N + 127) / 128;
    const int gs128 = (N + 31) / 32;   // segsum<128>: 32 nodes/block
    const int gs64  = (N + 63) / 64;   // segsum<64>:  64 nodes/block

    // ---- CSR build ----
    hist_k<<<1024, 256, 0, stream>>>(ei, cnt, E);
    bsum_k<<<G1, 256, 0, stream>>>(cnt, bsum, N);
    bscan_k<<<1, 256, 0, stream>>>(bsum, bpre, G1);
    offs_k<<<G1, 256, 0, stream>>>(cnt, bpre, off, cursor, N, E);
    fill_k<<<1024, 256, 0, stream>>>(ei, cursor, srcs, E);

    // ---- weight prep ----
    wprep_k<<<8, 256, 0, stream>>>(w1a, w1af, 128, 128);
    wprep_k<<<8, 256, 0, stream>>>(w1b, w1bf, 128, 128);
    wprep_k<<<4, 256, 0, stream>>>(w2a, w2af, 128, 64);
    wprep_k<<<2, 256, 0, stream>>>(w2b, w2bf, 64, 64);

    // ---- Layer 1 ----
    mgemm<128, 128, false, false, false, false, false, true>
        <<<gb, 256, 0, stream>>>(x, w1af, nullptr, nullptr, nullptr, p1, N);
    segsum_bf<128><<<gs128, 256, 0, stream>>>(p1, off, srcs, s1, sum1, sq1, N);
    bnfinal_k<<<1, 128, 0, stream>>>(sum1, sq1, g1, be1, sc1, sh1, 128, 1.f / N);
    mgemm<128, 128, true, true, true, true, false, true>
        <<<gb, 256, 0, stream>>>(s1, w1bf, sc1, sh1, b1b, h1, N);

    // ---- Layer 2 (aggregate after projecting to 64ch) ----
    mgemm<128, 64, true, false, false, false, false, true>
        <<<gb, 256, 0, stream>>>(h1, w2af, nullptr, nullptr, nullptr, p2, N);
    segsum_bf<64><<<gs64, 256, 0, stream>>>(p2, off, srcs, s2, sum2, sq2, N);
    bnfinal_k<<<1, 64, 0, stream>>>(sum2, sq2, g2, be2, sc2, sh2, 64, 1.f / N);
    mgemm<64, 64, true, true, true, false, true, false>
        <<<gb, 256, 0, stream>>>(s2, w2bf, sc2, sh2, b2b, out, N);
}

// Round 5
// 309.072 us; speedup vs baseline: 3.5670x; 1.0947x over previous
//
#include <hip/hip_runtime.h>

// ---------------------------------------------------------------------------
// GIN 2-layer forward (bf16 features, MFMA GEMMs, CSR gather segment-sum):
//   CSR bucket edges by dst (hist -> parallel scan -> fill)
//   p1 = bf16( x @ w1a )                      [b1a cancels in BN]
//   s1 = bf16( p1[n] + gather-sum )           (fused column stats)
//   h1 = bf16( relu( relu(sc1*s1+sh1) @ w1b + b1b ) )
//   p2 = bf16( h1 @ w2a )                     [b2a cancels in BN]
//   s2 = bf16( p2[n] + gather-sum )           (fused stats)
//   out = log_softmax( relu(sc2*s2+sh2) @ w2b + b2b )  fp32, fused epilogue
// segsum: wave-per-node, dword gathers, unroll-8 + index prefetch pipeline.
// ---------------------------------------------------------------------------

typedef unsigned short u16;
typedef unsigned int u32;
typedef __attribute__((ext_vector_type(8))) short short8;
typedef __attribute__((ext_vector_type(4))) short short4v;
typedef __attribute__((ext_vector_type(4))) float f32x4;

#define DEV_INLINE __device__ __forceinline__

DEV_INLINE void atomAddF(float* p, float v) { unsafeAtomicAdd(p, v); }

DEV_INLINE u16 f2bf(float f) {
    unsigned u = __float_as_uint(f);
    u += 0x7fffu + ((u >> 16) & 1u);   // round-to-nearest-even
    return (u16)(u >> 16);
}
DEV_INLINE float bf2f(u16 h) { return __uint_as_float(((unsigned)h) << 16); }

// ---------------------------------------------------------------------------
// Weight prep (all 4 weights in one launch): W[K][NOUT] fp32 -> frag-ordered
// bf16 (MFMA A-operand, swapped). unit=(ct,kc,lane): 8 bf16 for
// col=ct*16+(lane&15), k=kc*32+(lane>>4)*8+j.
// grid = 22 blocks: [0,8) w1a, [8,16) w1b, [16,20) w2a, [20,22) w2b.
// ---------------------------------------------------------------------------
__global__ __launch_bounds__(256) void wprep4_k(
    const float* __restrict__ w1a, const float* __restrict__ w1b,
    const float* __restrict__ w2a, const float* __restrict__ w2b,
    short* __restrict__ o1a, short* __restrict__ o1b,
    short* __restrict__ o2a, short* __restrict__ o2b)
{
    int b = blockIdx.x;
    const float* W; short* wf; int K, NOUT;
    if (b < 8)       { W = w1a; wf = o1a; K = 128; NOUT = 128; }
    else if (b < 16) { W = w1b; wf = o1b; K = 128; NOUT = 128; b -= 8; }
    else if (b < 20) { W = w2a; wf = o2a; K = 128; NOUT = 64;  b -= 16; }
    else             { W = w2b; wf = o2b; K = 64;  NOUT = 64;  b -= 20; }
    const int u = b * 256 + threadIdx.x;
    const int units = (NOUT / 16) * (K / 32) * 64;
    if (u >= units) return;
    const int per_ct = (K / 32) * 64;
    const int ct = u / per_ct;
    const int rem = u % per_ct;
    const int kc = rem >> 6;
    const int l = rem & 63;
    const int col = ct * 16 + (l & 15);
    const int k0 = kc * 32 + (l >> 4) * 8;
    short8 pk;
#pragma unroll
    for (int j = 0; j < 8; j++)
        pk[j] = (short)f2bf(W[(size_t)(k0 + j) * NOUT + col]);
    *(short8*)&wf[(size_t)u * 8] = pk;
}

// ---------------------------------------------------------------------------
// MFMA GEMM (swapped operands => per-lane contiguous C-writes):
//   out[M][NC] = f(A[M][KD]) @ W  (+bias) (+relu | +row log_softmax)
// A is fp32 or bf16; out is bf16 or fp32. BM=128 rows, 256 threads (4 waves).
// ---------------------------------------------------------------------------
template <int KD, int NC, bool ABF16, bool BNIN, bool BIAS, bool RELUOUT,
          bool LOGSM, bool OBF16>
__global__ __launch_bounds__(256) void mgemm(
    const void* __restrict__ Ap, const short* __restrict__ Wf,
    const float* __restrict__ sc, const float* __restrict__ sh,
    const float* __restrict__ bias, void* __restrict__ outp, int M)
{
    constexpr int BM = 128;
    constexpr int KC = KD / 32;   // 32-wide k chunks
    constexpr int CT = NC / 16;   // 16-wide col tiles
    __shared__ short Asl[BM * KD];
    __shared__ short Bsl[NC * KD];

    const int t = threadIdx.x;
    const int l = t & 63;
    const int w = t >> 6;

    // ---- stage B: frag-ordered weights, linear copy ----
    {
        const float4* src = (const float4*)Wf;
        float4* dst = (float4*)Bsl;
        constexpr int NU = NC * KD / 8;
#pragma unroll
        for (int u = t; u < NU; u += 256) dst[u] = src[u];
    }
    // ---- stage A: 2 threads per row -> (BN+ReLU) -> bf16 frags ----
    {
        const int r = t >> 1;
        const int half = t & 1;
        const int grow = blockIdx.x * BM + r;
        const int rt = r >> 4;
        constexpr int KH = KD / 2;
        u16 hv[KH];
        if (grow < M) {
            if constexpr (ABF16) {
                const u16* ap = (const u16*)Ap + (size_t)grow * KD + half * KH;
#pragma unroll
                for (int i = 0; i < KH / 8; i++)
                    *(short8*)&hv[i * 8] = ((const short8*)ap)[i];
                if constexpr (BNIN) {
#pragma unroll
                    for (int i = 0; i < KH; i++) {
                        const int k = half * KH + i;
                        hv[i] = f2bf(fmaxf(0.f, bf2f(hv[i]) * sc[k] + sh[k]));
                    }
                }
            } else {
                const float* ap = (const float*)Ap + (size_t)grow * KD + half * KH;
#pragma unroll
                for (int i = 0; i < KH / 4; i++) {
                    const float4 v = ((const float4*)ap)[i];
                    float f0 = v.x, f1 = v.y, f2 = v.z, f3 = v.w;
                    if constexpr (BNIN) {
                        const int k = half * KH + i * 4;
                        f0 = fmaxf(0.f, f0 * sc[k + 0] + sh[k + 0]);
                        f1 = fmaxf(0.f, f1 * sc[k + 1] + sh[k + 1]);
                        f2 = fmaxf(0.f, f2 * sc[k + 2] + sh[k + 2]);
                        f3 = fmaxf(0.f, f3 * sc[k + 3] + sh[k + 3]);
                    }
                    hv[i * 4 + 0] = f2bf(f0); hv[i * 4 + 1] = f2bf(f1);
                    hv[i * 4 + 2] = f2bf(f2); hv[i * 4 + 3] = f2bf(f3);
                }
            }
        } else {
#pragma unroll
            for (int i = 0; i < KH; i++) hv[i] = 0;
        }
#pragma unroll
        for (int g = 0; g < KH / 8; g++) {
            const int k0 = half * KH + g * 8;
            const int kc = k0 >> 5;
            const int lane = (r & 15) + ((k0 >> 3) & 3) * 16;
            *(short8*)&Asl[((rt * KC + kc) * 64 + lane) * 8] =
                *(short8*)&hv[g * 8];
        }
    }
    __syncthreads();

    // ---- MFMA: wave w owns row-tiles {2w, 2w+1} x all col-tiles ----
    const int rt0 = w * 2;
    f32x4 acc[2][CT];
#pragma unroll
    for (int i = 0; i < 2; i++)
#pragma unroll
        for (int c = 0; c < CT; c++) acc[i][c] = (f32x4){0.f, 0.f, 0.f, 0.f};

#pragma unroll
    for (int kc = 0; kc < KC; kc++) {
        const short8 x0 = *(const short8*)&Asl[((rt0 * KC + kc) * 64 + l) * 8];
        const short8 x1 = *(const short8*)&Asl[(((rt0 + 1) * KC + kc) * 64 + l) * 8];
#pragma unroll
        for (int ct = 0; ct < CT; ct++) {
            const short8 wb = *(const short8*)&Bsl[((ct * KC + kc) * 64 + l) * 8];
            acc[0][ct] = __builtin_amdgcn_mfma_f32_16x16x32_bf16(wb, x0, acc[0][ct], 0, 0, 0);
            acc[1][ct] = __builtin_amdgcn_mfma_f32_16x16x32_bf16(wb, x1, acc[1][ct], 0, 0, 0);
        }
    }

    // ---- epilogue: lane l holds row (l&15), cols (l>>4)*4+{0..3} of tile ----
    const int cbase = (l >> 4) * 4;
#pragma unroll
    for (int rr = 0; rr < 2; rr++) {
        const int grow = blockIdx.x * BM + (rt0 + rr) * 16 + (l & 15);
        if constexpr (!LOGSM) {
            if (grow < M) {
#pragma unroll
                for (int ct = 0; ct < CT; ct++) {
                    f32x4 o = acc[rr][ct];
                    if constexpr (BIAS) {
                        const float4 bv = *(const float4*)&bias[ct * 16 + cbase];
                        o[0] += bv.x; o[1] += bv.y; o[2] += bv.z; o[3] += bv.w;
                    }
                    if constexpr (RELUOUT) {
#pragma unroll
                        for (int j = 0; j < 4; j++) o[j] = fmaxf(o[j], 0.f);
                    }
                    if constexpr (OBF16) {
                        short4v o16;
#pragma unroll
                        for (int j = 0; j < 4; j++) o16[j] = (short)f2bf(o[j]);
                        *(short4v*)&((u16*)outp)[(size_t)grow * NC + ct * 16 + cbase] = o16;
                    } else {
                        *(f32x4*)&((float*)outp)[(size_t)grow * NC + ct * 16 + cbase] = o;
                    }
                }
            }
        } else {
            // fused row log_softmax (row spread across lanes l, l^16, l^32, l^48)
            float v[CT * 4];
#pragma unroll
            for (int ct = 0; ct < CT; ct++) {
                const float4 bv = *(const float4*)&bias[ct * 16 + cbase];
                v[ct * 4 + 0] = acc[rr][ct][0] + bv.x;
                v[ct * 4 + 1] = acc[rr][ct][1] + bv.y;
                v[ct * 4 + 2] = acc[rr][ct][2] + bv.z;
                v[ct * 4 + 3] = acc[rr][ct][3] + bv.w;
            }
            float m = v[0];
#pragma unroll
            for (int j = 1; j < CT * 4; j++) m = fmaxf(m, v[j]);
            m = fmaxf(m, __shfl_xor(m, 16));
            m = fmaxf(m, __shfl_xor(m, 32));
            float s = 0.f;
#pragma unroll
            for (int j = 0; j < CT * 4; j++) s += __expf(v[j] - m);
            s += __shfl_xor(s, 16);
            s += __shfl_xor(s, 32);
            const float lg = m + __logf(s);
            if (grow < M) {
#pragma unroll
                for (int ct = 0; ct < CT; ct++) {
                    f32x4 o;
#pragma unroll
                    for (int j = 0; j < 4; j++) o[j] = v[ct * 4 + j] - lg;
                    *(f32x4*)&((float*)outp)[(size_t)grow * NC + ct * 16 + cbase] = o;
                }
            }
        }
    }
}

// ---------------------------------------------------------------------------
// CSR build: histogram, 3-kernel parallel exclusive scan, bucket fill.
// ---------------------------------------------------------------------------
__global__ __launch_bounds__(256) void hist_k(const int* __restrict__ ei,
                                              int* __restrict__ cnt, int E)
{
    const int gid = blockIdx.x * blockDim.x + threadIdx.x;
    const int stride = gridDim.x * blockDim.x;
    for (int e = gid; e < E; e += stride) atomicAdd(&cnt[ei[E + e]], 1);
}

__global__ __launch_bounds__(256) void bsum_k(const int* __restrict__ cnt,
                                              int* __restrict__ bsum, int N)
{
    __shared__ int ws[4];
    const int i = blockIdx.x * 256 + threadIdx.x;
    int v = (i < N) ? cnt[i] : 0;
    for (int d = 32; d; d >>= 1) v += __shfl_xor(v, d, 64);
    if ((threadIdx.x & 63) == 0) ws[threadIdx.x >> 6] = v;
    __syncthreads();
    if (threadIdx.x == 0) bsum[blockIdx.x] = ws[0] + ws[1] + ws[2] + ws[3];
}

// single block; G1 <= 256
__global__ __launch_bounds__(256) void bscan_k(const int* __restrict__ bsum,
                                               int* __restrict__ bpre, int G1)
{
    __shared__ int part[256];
    const int t = threadIdx.x;
    const int v = (t < G1) ? bsum[t] : 0;
    part[t] = v;
    __syncthreads();
    for (int d = 1; d < 256; d <<= 1) {
        const int u = (t >= d) ? part[t - d] : 0;
        __syncthreads();
        part[t] += u;
        __syncthreads();
    }
    bpre[t] = part[t] - v;   // exclusive
}

__global__ __launch_bounds__(256) void offs_k(const int* __restrict__ cnt,
                                              const int* __restrict__ bpre,
                                              int* __restrict__ off,
                                              int* __restrict__ cursor,
                                              int N, int E)
{
    __shared__ int part[256];
    const int t = threadIdx.x;
    const int i = blockIdx.x * 256 + t;
    const int v = (i < N) ? cnt[i] : 0;
    part[t] = v;
    __syncthreads();
    for (int d = 1; d < 256; d <<= 1) {
        const int u = (t >= d) ? part[t - d] : 0;
        __syncthreads();
        part[t] += u;
        __syncthreads();
    }
    if (i < N) {
        const int o = bpre[blockIdx.x] + part[t] - v;
        off[i] = o;
        cursor[i] = o;
    }
    if (blockIdx.x == 0 && t == 0) off[N] = E;
}

__global__ __launch_bounds__(256) void fill_k(const int* __restrict__ ei,
                                              int* __restrict__ cursor,
                                              int* __restrict__ srcs, int E)
{
    const int gid = blockIdx.x * blockDim.x + threadIdx.x;
    const int stride = gridDim.x * blockDim.x;
    for (int e = gid; e < E; e += stride) {
        const int s = ei[e];
        const int d = ei[E + e];
        const int pos = atomicAdd(&cursor[d], 1);
        srcs[pos] = s;
    }
}

// ---------------------------------------------------------------------------
// Gather segment-sum (bf16 in/out) + fused column stats.
// One WAVE per node: C=128 -> lane carries 2 channels (dword gathers);
// C=64 -> lane = channel (ushort gathers). Unroll-8 gather with software-
// pipelined srcs-index prefetch; tail masked via clamped index + cndmask.
// ---------------------------------------------------------------------------
template <int C>
__global__ __launch_bounds__(256) void segsum_bf(
    const u16* __restrict__ p, const int* __restrict__ off,
    const int* __restrict__ srcs, u16* __restrict__ out,
    float* __restrict__ sum, float* __restrict__ sumsq, int N)
{
    constexpr int BLKN = 8;            // nodes per wave
    constexpr int VPL = C / 64;        // channels per lane (2 or 1)
    __shared__ float red[4][64][2 * VPL];

    const int wv = threadIdx.x >> 6;
    const int l  = threadIdx.x & 63;
    const int base = blockIdx.x * 4 * BLKN;

    float ss[VPL], qq[VPL];
#pragma unroll
    for (int v = 0; v < VPL; v++) { ss[v] = 0.f; qq[v] = 0.f; }

    for (int i = 0; i < BLKN; i++) {
        const int n = base + i * 4 + wv;
        if (n < N) {
            const int lo = __builtin_amdgcn_readfirstlane(off[n]);
            const int hi = __builtin_amdgcn_readfirstlane(off[n + 1]);
            float acc[VPL];
            if constexpr (VPL == 2) {
                const u32 u = *(const u32*)&p[(size_t)n * C + 2 * l];
                acc[0] = bf2f((u16)u);
                acc[1] = bf2f((u16)(u >> 16));
            } else {
                acc[0] = bf2f(p[(size_t)n * C + l]);
            }
            const int cnt = hi - lo;
            if (cnt > 0) {
                const int last = hi - 1;
                int idx[8];
#pragma unroll
                for (int j = 0; j < 8; j++) idx[j] = srcs[min(lo + j, last)];
                for (int e = lo; e < hi; e += 8) {
                    int nx[8];
#pragma unroll
                    for (int j = 0; j < 8; j++)
                        nx[j] = srcs[min(e + 8 + j, last)];   // prefetch next
#pragma unroll
                    for (int j = 0; j < 8; j++) {
                        const bool live = (e + j) < hi;
                        if constexpr (VPL == 2) {
                            const u32 u = *(const u32*)&p[(size_t)idx[j] * C + 2 * l];
                            const float v0 = bf2f((u16)u);
                            const float v1 = bf2f((u16)(u >> 16));
                            acc[0] += live ? v0 : 0.f;
                            acc[1] += live ? v1 : 0.f;
                        } else {
                            const float v = bf2f(p[(size_t)idx[j] * C + l]);
                            acc[0] += live ? v : 0.f;
                        }
                    }
#pragma unroll
                    for (int j = 0; j < 8; j++) idx[j] = nx[j];
                }
            }
            // store rounded + stats on the rounded values
            if constexpr (VPL == 2) {
                const u16 r0 = f2bf(acc[0]);
                const u16 r1 = f2bf(acc[1]);
                *(u32*)&out[(size_t)n * C + 2 * l] = (u32)r0 | ((u32)r1 << 16);
                const float f0 = bf2f(r0), f1 = bf2f(r1);
                ss[0] += f0; qq[0] += f0 * f0;
                ss[1] += f1; qq[1] += f1 * f1;
            } else {
                const u16 r = f2bf(acc[0]);
                out[(size_t)n * C + l] = r;
                const float f = bf2f(r);
                ss[0] += f; qq[0] += f * f;
            }
        }
    }

    // block reduce across the 4 waves, one atomic per channel per block
#pragma unroll
    for (int v = 0; v < VPL; v++) {
        red[wv][l][2 * v] = ss[v];
        red[wv][l][2 * v + 1] = qq[v];
    }
    __syncthreads();
    if (wv == 0) {
#pragma unroll
        for (int v = 0; v < VPL; v++) {
            float a = 0.f, b = 0.f;
#pragma unroll
            for (int w2 = 0; w2 < 4; w2++) {
                a += red[w2][l][2 * v];
                b += red[w2][l][2 * v + 1];
            }
            const int ch = (VPL == 2) ? (2 * l + v) : l;
            atomAddF(&sum[ch], a);
            atomAddF(&sumsq[ch], b);
        }
    }
}

__global__ void bnfinal_k(const float* __restrict__ sum,
                          const float* __restrict__ sumsq,
                          const float* __restrict__ g,
                          const float* __restrict__ be,
                          float* __restrict__ sc, float* __restrict__ sh,
                          int C, float invN)
{
    const int c = threadIdx.x;
    if (c < C) {
        const float m = sum[c] * invN;
        const float v = sumsq[c] * invN - m * m;
        const float r = rsqrtf(v + 1e-5f);
        const float s = g[c] * r;
        sc[c] = s;
        sh[c] = be[c] - m * s;
    }
}

extern "C" void kernel_launch(void* const* d_in, const int* in_sizes, int n_in,
                              void* d_out, int out_size, void* d_ws, size_t ws_size,
                              hipStream_t stream)
{
    const float* x   = (const float*)d_in[0];
    const int*   ei  = (const int*)d_in[1];
    const float* w1a = (const float*)d_in[2];
    // d_in[3] = b1a: cancelled by BN
    const float* g1  = (const float*)d_in[4];
    const float* be1 = (const float*)d_in[5];
    const float* w1b = (const float*)d_in[6];
    const float* b1b = (const float*)d_in[7];
    const float* w2a = (const float*)d_in[8];
    // d_in[9] = b2a: cancelled by BN
    const float* g2  = (const float*)d_in[10];
    const float* be2 = (const float*)d_in[11];
    const float* w2b = (const float*)d_in[12];
    const float* b2b = (const float*)d_in[13];
    float* out = (float*)d_out;

    const int N = in_sizes[0] / 128;   // 50000
    const int E = in_sizes[1] / 2;     // 800000

    // ---- workspace layout ----
    u16* buf1 = (u16*)d_ws;                      // N*128 bf16 : p1, then h1
    u16* buf2 = buf1 + (size_t)N * 128;          // N*128 bf16 : s1, then p2|s2
    float* stats = (float*)(buf2 + (size_t)N * 128);  // 1024 floats
    float* sum1 = stats,       *sq1 = stats + 128;
    float* sum2 = stats + 256, *sq2 = stats + 320;
    float* sc1  = stats + 384, *sh1 = stats + 512;
    float* sc2  = stats + 640, *sh2 = stats + 704;
    int* cnt    = (int*)(stats + 1024);          // N
    int* off    = cnt + N;                       // N+1
    int* cursor = off + N + 1;                   // N
    int* srcs   = cursor + N;                    // E
    int* bsum   = srcs + E;                      // 256
    int* bpre   = bsum + 256;                    // 256
    short* w1af = (short*)(bpre + 256);          // 128*128
    short* w1bf = w1af + 128 * 128;              // 128*128
    short* w2af = w1bf + 128 * 128;              // 128*64
    short* w2bf = w2af + 128 * 64;               // 64*64
    u16* p1 = buf1;
    u16* s1 = buf2;
    u16* h1 = buf1;                    // reuse: p1 dead after segsum1
    u16* p2 = buf2;                    // reuse: s1 dead after mgemm2 (N*64)
    u16* s2 = buf2 + (size_t)N * 64;   // upper half

    hipMemsetAsync(stats, 0, 1024 * sizeof(float) + (size_t)N * sizeof(int), stream);

    const int G1 = (N + 255) / 256;
    const int gb = (N + 127) / 128;
    const int gs = (N + 31) / 32;      // segsum: 4 waves x 8 nodes per block

    // ---- CSR build ----
    hist_k<<<1024, 256, 0, stream>>>(ei, cnt, E);
    bsum_k<<<G1, 256, 0, stream>>>(cnt, bsum, N);
    bscan_k<<<1, 256, 0, stream>>>(bsum, bpre, G1);
    offs_k<<<G1, 256, 0, stream>>>(cnt, bpre, off, cursor, N, E);
    fill_k<<<1024, 256, 0, stream>>>(ei, cursor, srcs, E);

    // ---- weight prep (one launch for all four) ----
    wprep4_k<<<22, 256, 0, stream>>>(w1a, w1b, w2a, w2b, w1af, w1bf, w2af, w2bf);

    // ---- Layer 1 ----
    mgemm<128, 128, false, false, false, false, false, true>
        <<<gb, 256, 0, stream>>>(x, w1af, nullptr, nullptr, nullptr, p1, N);
    segsum_bf<128><<<gs, 256, 0, stream>>>(p1, off, srcs, s1, sum1, sq1, N);
    bnfinal_k<<<1, 128, 0, stream>>>(sum1, sq1, g1, be1, sc1, sh1, 128, 1.f / N);
    mgemm<128, 128, true, true, true, true, false, true>
        <<<gb, 256, 0, stream>>>(s1, w1bf, sc1, sh1, b1b, h1, N);

    // ---- Layer 2 (aggregate after projecting to 64ch) ----
    mgemm<128, 64, true, false, false, false, false, true>
        <<<gb, 256, 0, stream>>>(h1, w2af, nullptr, nullptr, nullptr, p2, N);
    segsum_bf<64><<<gs, 256, 0, stream>>>(p2, off, srcs, s2, sum2, sq2, N);
    bnfinal_k<<<1, 64, 0, stream>>>(sum2, sq2, g2, be2, sc2, sh2, 64, 1.f / N);
    mgemm<64, 64, true, true, true, false, true, false>
        <<<gb, 256, 0, stream>>>(s2, w2bf, sc2, sh2, b2b, out, N);
}